// Round 1
// baseline (189.209 us; speedup 1.0000x reference)
//
#include <hip/hip_runtime.h>
#include <hip/hip_bf16.h>

typedef __attribute__((ext_vector_type(8))) short short8;
typedef __attribute__((ext_vector_type(4))) float f32x4;
typedef unsigned short ushort_t;
typedef unsigned int uint_t;

#define D_MODEL 512
#define D_ATTN  64
#define R1      16   // rows per block, projection kernel
// sequence length fixed at 1024, batch 8

__device__ __forceinline__ ushort_t f2bf(float f) {
    // round-to-nearest-even bf16 (inputs are finite, no NaN handling needed)
    uint_t u = __float_as_uint(f);
    u += 0x7FFFu + ((u >> 16) & 1u);
    return (ushort_t)(u >> 16);
}

// ---------------- Kernel 1: QKV projection ----------------
// grid 512 blocks x 192 threads. wave 0->Q, wave 1->K, wave 2->V. lane = d.
// x addresses are wave-uniform -> scalar loads; VALU does pure FMA.
__global__ __launch_bounds__(192)
void qkv_proj(const float* __restrict__ x,
              const float* __restrict__ Wq, const float* __restrict__ bq,
              const float* __restrict__ Wk, const float* __restrict__ bk,
              const float* __restrict__ Wv, const float* __restrict__ bv,
              ushort_t* __restrict__ Q, ushort_t* __restrict__ K,
              ushort_t* __restrict__ Vt)
{
    const int wv   = threadIdx.x >> 6;
    const int lane = threadIdx.x & 63;
    const size_t row0 = (size_t)blockIdx.x * R1;
    const float* __restrict__ xb = x + row0 * D_MODEL;
    const float* __restrict__ W  = (wv == 0) ? Wq : ((wv == 1) ? Wk : Wv);

    float acc[R1];
#pragma unroll
    for (int r = 0; r < R1; ++r) acc[r] = 0.0f;

    for (int k = 0; k < D_MODEL; k += 4) {
        float w0 = W[(k + 0) * D_ATTN + lane];
        float w1 = W[(k + 1) * D_ATTN + lane];
        float w2 = W[(k + 2) * D_ATTN + lane];
        float w3 = W[(k + 3) * D_ATTN + lane];
#pragma unroll
        for (int r = 0; r < R1; ++r) {
            float4 xv = *(const float4*)(xb + r * D_MODEL + k);  // uniform -> s_load
            acc[r] = fmaf(xv.x, w0, acc[r]);
            acc[r] = fmaf(xv.y, w1, acc[r]);
            acc[r] = fmaf(xv.z, w2, acc[r]);
            acc[r] = fmaf(xv.w, w3, acc[r]);
        }
    }

    if (wv == 0) {
        float bias = bq[lane];
#pragma unroll
        for (int r = 0; r < R1; ++r)
            Q[(row0 + r) * D_ATTN + lane] = f2bf((acc[r] + bias) * 0.125f); // fold 1/sqrt(64)
    } else if (wv == 1) {
        float bias = bk[lane];
#pragma unroll
        for (int r = 0; r < R1; ++r)
            K[(row0 + r) * D_ATTN + lane] = f2bf(acc[r] + bias);
    } else {
        float bias = bv[lane];
        uint_t pk[8];
#pragma unroll
        for (int r = 0; r < R1; r += 2)
            pk[r >> 1] = (uint_t)f2bf(acc[r] + bias) |
                         ((uint_t)f2bf(acc[r + 1] + bias) << 16);
        const int bb = (int)(row0 >> 10);
        const int n0 = (int)(row0 & 1023);
        // V transposed: Vt[b][d][n], 16 consecutive n per lane -> 2x16B stores
        uint4* dst = (uint4*)(Vt + ((size_t)bb * 64 + lane) * 1024 + n0);
        dst[0] = make_uint4(pk[0], pk[1], pk[2], pk[3]);
        dst[1] = make_uint4(pk[4], pk[5], pk[6], pk[7]);
    }
}

// ---------------- Kernel 2: fused topological attention ----------------
// grid 512 blocks (b * 64 row-tiles) x 256 threads (4 waves).
// LDS 64KB: logits f32[16][1024]; P bf16[16][1024] aliases bytes [0,32K);
// per-wave partial outs f32[4][16][64] alias bytes [32K,48K).
__global__ __launch_bounds__(256)
void topo_attn(const float* __restrict__ top, const float* __restrict__ Wt,
               const ushort_t* __restrict__ Q, const ushort_t* __restrict__ K,
               const ushort_t* __restrict__ Vt, float* __restrict__ out)
{
    __shared__ float lds[16384];
    const int tid = threadIdx.x;
    const int b   = blockIdx.x >> 6;
    const int bn0 = blockIdx.x << 4;   // b*1024 + n0

    // ---- Phase A: bias[r][m] = top[b][n0+r][m][:] . Wt  (the 512MB stream) ----
    float wt[16];
#pragma unroll
    for (int i = 0; i < 16; ++i) wt[i] = Wt[i];
    const float* __restrict__ topb = top + ((size_t)bn0 << 14);
#pragma unroll 2
    for (int it = 0; it < 64; ++it) {
        int r = it >> 2;
        int m = ((it & 3) << 8) + tid;
        const float4* tp = (const float4*)(topb + (((size_t)r) << 14) + ((size_t)m << 4));
        float4 a = tp[0], b4 = tp[1], c4 = tp[2], d4 = tp[3];
        float s = a.x * wt[0];
        s = fmaf(a.y,  wt[1],  s); s = fmaf(a.z,  wt[2],  s); s = fmaf(a.w,  wt[3],  s);
        s = fmaf(b4.x, wt[4],  s); s = fmaf(b4.y, wt[5],  s); s = fmaf(b4.z, wt[6],  s);
        s = fmaf(b4.w, wt[7],  s); s = fmaf(c4.x, wt[8],  s); s = fmaf(c4.y, wt[9],  s);
        s = fmaf(c4.z, wt[10], s); s = fmaf(c4.w, wt[11], s); s = fmaf(d4.x, wt[12], s);
        s = fmaf(d4.y, wt[13], s); s = fmaf(d4.z, wt[14], s); s = fmaf(d4.w, wt[15], s);
        lds[r * 1024 + m] = s;   // bt dropped: softmax shift-invariant
    }
    __syncthreads();

    // ---- Phase B: logits += (Q/8) K^T via MFMA ----
    const int l = tid & 63, wv = tid >> 6;
    const int lr = l & 15, lg = l >> 4;
    const short8 a0 = *(const short8*)(Q + ((size_t)(bn0 + lr)) * 64 + 8 * lg);
    const short8 a1 = *(const short8*)(Q + ((size_t)(bn0 + lr)) * 64 + 32 + 8 * lg);
    const ushort_t* __restrict__ Kb = K + ((size_t)b << 16);
#pragma unroll 4
    for (int t16 = 0; t16 < 16; ++t16) {
        int m0 = (wv << 8) + (t16 << 4);
        short8 kb0 = *(const short8*)(Kb + (size_t)(m0 + lr) * 64 + 8 * lg);
        short8 kb1 = *(const short8*)(Kb + (size_t)(m0 + lr) * 64 + 32 + 8 * lg);
        f32x4 acc = {0.f, 0.f, 0.f, 0.f};
        acc = __builtin_amdgcn_mfma_f32_16x16x32_bf16(a0, kb0, acc, 0, 0, 0);
        acc = __builtin_amdgcn_mfma_f32_16x16x32_bf16(a1, kb1, acc, 0, 0, 0);
#pragma unroll
        for (int j = 0; j < 4; ++j)
            lds[(4 * lg + j) * 1024 + m0 + lr] += acc[j];  // C/D: col=lane&15, row=4*(l>>4)+j
    }
    __syncthreads();

    // ---- Phase C: row softmax; write P (bf16) aliased over logits[0:32KB) ----
    {
        const int r = tid >> 4, sseg = tid & 15;
        float4 v4[16];
        const float4* rowp = (const float4*)(lds + r * 1024 + sseg * 64);
#pragma unroll
        for (int i = 0; i < 16; ++i) v4[i] = rowp[i];
        __syncthreads();   // everyone finished reading logits before alias overwrite
        float mx = v4[0].x;
#pragma unroll
        for (int i = 0; i < 16; ++i)
            mx = fmaxf(mx, fmaxf(fmaxf(v4[i].x, v4[i].y), fmaxf(v4[i].z, v4[i].w)));
#pragma unroll
        for (int off = 8; off >= 1; off >>= 1) mx = fmaxf(mx, __shfl_xor(mx, off));
        float sum = 0.f;
#pragma unroll
        for (int i = 0; i < 16; ++i) {
            v4[i].x = __expf(v4[i].x - mx); sum += v4[i].x;
            v4[i].y = __expf(v4[i].y - mx); sum += v4[i].y;
            v4[i].z = __expf(v4[i].z - mx); sum += v4[i].z;
            v4[i].w = __expf(v4[i].w - mx); sum += v4[i].w;
        }
#pragma unroll
        for (int off = 8; off >= 1; off >>= 1) sum += __shfl_xor(sum, off);
        float inv = 1.0f / sum;
        ushort_t* pb = ((ushort_t*)lds) + r * 1024 + sseg * 64;
#pragma unroll
        for (int i = 0; i < 8; ++i) {
            uint_t w0 = (uint_t)f2bf(v4[2*i].x * inv)   | ((uint_t)f2bf(v4[2*i].y * inv)   << 16);
            uint_t w1 = (uint_t)f2bf(v4[2*i].z * inv)   | ((uint_t)f2bf(v4[2*i].w * inv)   << 16);
            uint_t w2 = (uint_t)f2bf(v4[2*i+1].x * inv) | ((uint_t)f2bf(v4[2*i+1].y * inv) << 16);
            uint_t w3 = (uint_t)f2bf(v4[2*i+1].z * inv) | ((uint_t)f2bf(v4[2*i+1].w * inv) << 16);
            ((uint4*)pb)[i] = make_uint4(w0, w1, w2, w3);
        }
    }
    __syncthreads();

    // ---- Phase D: out = P V  (V transposed -> contiguous B-frag loads) ----
    {
        f32x4 o[4] = {{0,0,0,0},{0,0,0,0},{0,0,0,0},{0,0,0,0}};
        const ushort_t* __restrict__ pb = ((const ushort_t*)lds) + lr * 1024;
        const ushort_t* __restrict__ Vb = Vt + ((size_t)b << 16);
#pragma unroll 2
        for (int c = 0; c < 8; ++c) {
            int m0 = (wv << 8) + (c << 5) + 8 * lg;
            short8 pa = *(const short8*)(pb + m0);
#pragma unroll
            for (int dt = 0; dt < 4; ++dt) {
                short8 vb = *(const short8*)(Vb + (size_t)(dt * 16 + lr) * 1024 + m0);
                o[dt] = __builtin_amdgcn_mfma_f32_16x16x32_bf16(pa, vb, o[dt], 0, 0, 0);
            }
        }
        float* lo = lds + 8192 + (wv << 10);   // partial out, disjoint from P
#pragma unroll
        for (int dt = 0; dt < 4; ++dt)
#pragma unroll
            for (int j = 0; j < 4; ++j)
                lo[(4 * lg + j) * 64 + dt * 16 + lr] = o[dt][j];
    }
    __syncthreads();

    // ---- cross-wave reduce + coalesced store ----
#pragma unroll
    for (int i = 0; i < 4; ++i) {
        int idx = (i << 8) + tid;   // r*64 + d
        float s2 = lds[8192 + idx] + lds[8192 + 1024 + idx]
                 + lds[8192 + 2048 + idx] + lds[8192 + 3072 + idx];
        out[((size_t)bn0 << 6) + idx] = s2;
    }
}

extern "C" void kernel_launch(void* const* d_in, const int* in_sizes, int n_in,
                              void* d_out, int out_size, void* d_ws, size_t ws_size,
                              hipStream_t stream) {
    const float* x   = (const float*)d_in[0];
    const float* top = (const float*)d_in[1];
    const float* Wq  = (const float*)d_in[2];
    const float* bq  = (const float*)d_in[3];
    const float* Wk  = (const float*)d_in[4];
    const float* bk  = (const float*)d_in[5];
    const float* Wv  = (const float*)d_in[6];
    const float* bv  = (const float*)d_in[7];
    const float* Wt  = (const float*)d_in[8];
    // d_in[9] = bt: constant added to every logit -> softmax-invariant, dropped.
    float* out = (float*)d_out;

    ushort_t* Q  = (ushort_t*)d_ws;          // [8][1024][64] bf16 (pre-scaled 1/8)
    ushort_t* K  = Q + 8 * 1024 * 64;        // [8][1024][64] bf16
    ushort_t* Vt = K + 8 * 1024 * 64;        // [8][64][1024] bf16 (transposed)

    qkv_proj<<<512, 192, 0, stream>>>(x, Wq, bq, Wk, bk, Wv, bv, Q, K, Vt);
    topo_attn<<<512, 256, 0, stream>>>(top, Wt, Q, K, Vt, out);
}